// Round 2
// baseline (544.023 us; speedup 1.0000x reference)
//
#include <hip/hip_runtime.h>
#include <cstdint>
#include <cstddef>

// PositionalEncoderGrid: Instant-NGP multiresolution hash grid.
// B=524288 points, L=16 levels, T=2^19 entries/level, F=2 floats.
//
// R9: - Single persistent-block phase-A kernel with dynamic work grabbing.
//       R8 showed per-gather cost is invariant (~3 cyc/lane-request) and the
//       2-pass schedule wastes ~0.4C of XCD time (pass 2 bounded by l6/l7
//       while coarse XCDs idle). New schedule: 10 fine levels (l6-l15) split
//       into quarters, pinned 1.25 levels per XCD (<=2 tables, sequential ->
//       L2 residency kept); coarse l0-l5 in 8 per-XCD pools drained after
//       pinned work, with stealing. Atomic grab-ahead hides counter latency.
//     - x-pair dwordx4 trick: corners (x0,c) and (x1,c) satisfy i1 == i0^1
//       when px is even (px+1 flips only bit 0; XOR commutes with the mask),
//       and {i&~1, i|1} is an aligned 16B pair -> one dwordx4 instead of two
//       dwordx2. Odd-px lanes take a divergent 4-load fallback. Expected
//       requests/pt: 8 -> 6 (diagnostic for the request-throughput model).
//     - Work counters live in the first 2KB of d_out (128B apart); transpose
//       overwrites them afterwards. Tiny init kernel zeroes them.
//     - Phase B transpose unchanged.

#define NUM_LEVELS 16
#define TBL_MASK ((1u << 19) - 1u)
#define PRIME_Y 2654435761u
#define PRIME_Z 805459861u
#define BATCH 524288
#define PINNED_TOTAL 10240      // units of 64 points: 1.25 levels * 8192
#define COARSE_POOL 6144        // per-pool units: 6 levels * 1024

typedef float nfloat4 __attribute__((ext_vector_type(4)));
typedef double ndouble2 __attribute__((ext_vector_type(2)));

__constant__ float c_ns[NUM_LEVELS] = {
    16.f, 20.f, 25.f, 32.f, 40.f, 50.f, 64.f, 80.f,
    101.f, 128.f, 161.f, 203.f, 256.f, 322.f, 406.f, 512.f
};

// Pinned schedule: XCD i gets 1.25 fine levels as quarters (units of 64 pts).
// Each XCD touches <=2 distinct 4MiB tables, sequentially.
typedef struct { int level; int base; int count; } Seg;
__constant__ Seg c_pinned[8][2] = {
    {{ 6,    0, 8192}, { 7,    0, 2048}},
    {{ 7, 2048, 6144}, { 8,    0, 4096}},
    {{ 8, 4096, 4096}, { 9,    0, 6144}},
    {{ 9, 6144, 2048}, {10,    0, 8192}},
    {{11,    0, 8192}, {12,    0, 2048}},
    {{12, 2048, 6144}, {13,    0, 4096}},
    {{13, 4096, 4096}, {14,    0, 6144}},
    {{14, 6144, 2048}, {15,    0, 8192}},
};

__device__ __forceinline__ float2 d2f2(double d) {
    union { double d; float2 f; } u;
    u.d = d;
    return u.f;
}

__device__ __forceinline__ double f22d(float2 f) {
    union { double d; float2 f; } u;
    u.f = f;
    return u.d;
}

// One 64-point unit at one level. l, unit are wave-uniform.
__device__ __forceinline__ void process_unit(
    int l, int unit, int lane,
    const float* __restrict__ in,
    const float* __restrict__ table,
    double* __restrict__ ws)
{
    const int p = unit * 64 + lane;
    const float vx = __builtin_nontemporal_load(&in[p * 3 + 0]);
    const float vy = __builtin_nontemporal_load(&in[p * 3 + 1]);
    const float vz = __builtin_nontemporal_load(&in[p * 3 + 2]);
    // Keep exact expression order from the verified R8 kernel.
    const float xs = (vx + 3.0f) / 6.0f;
    const float ys = (vy + 3.0f) / 6.0f;
    const float zs = (vz + 3.0f) / 6.0f;
    const float n = c_ns[l];
    const float tx = xs * n, ty = ys * n, tz = zs * n;
    const float fpx = floorf(tx), fpy = floorf(ty), fpz = floorf(tz);
    const float wx1 = tx - fpx, wy1 = ty - fpy, wz1 = tz - fpz;
    const uint32_t px = (uint32_t)fpx;
    const uint32_t py = (uint32_t)fpy;
    const uint32_t pz = (uint32_t)fpz;

    const uint32_t hy0 = py * PRIME_Y, hy1 = hy0 + PRIME_Y;
    const uint32_t hz0 = pz * PRIME_Z, hz1 = hz0 + PRIME_Z;
    const uint32_t b0 = hy0 ^ hz0, b1 = hy0 ^ hz1;
    const uint32_t b2 = hy1 ^ hz0, b3 = hy1 ^ hz1;

    const uint32_t i00 = (px ^ b0) & TBL_MASK;
    const uint32_t i01 = (px ^ b1) & TBL_MASK;
    const uint32_t i02 = (px ^ b2) & TBL_MASK;
    const uint32_t i03 = (px ^ b3) & TBL_MASK;
    const uint32_t qx = px + 1u;
    const uint32_t i40 = (qx ^ b0) & TBL_MASK;
    const uint32_t i41 = (qx ^ b1) & TBL_MASK;
    const uint32_t i42 = (qx ^ b2) & TBL_MASK;
    const uint32_t i43 = (qx ^ b3) & TBL_MASK;

    const double* __restrict__ tb = ((const double*)table) + ((size_t)l << 19);
    const ndouble2* __restrict__ tb2 = (const ndouble2*)tb;

    // x0 corners via aligned 16B pair loads (also yields the x1 partner
    // when px is even, since then i4 == i0^1).
    const ndouble2 q0 = tb2[i00 >> 1];
    const ndouble2 q1 = tb2[i01 >> 1];
    const ndouble2 q2 = tb2[i02 >> 1];
    const ndouble2 q3 = tb2[i03 >> 1];

    const bool odd = (px & 1u) != 0u;
    double g0 = 0.0, g1 = 0.0, g2 = 0.0, g3 = 0.0;
    if (odd) {   // divergent: only odd-px lanes issue these 4 gathers
        g0 = tb[i40];
        g1 = tb[i41];
        g2 = tb[i42];
        g3 = tb[i43];
    }

    const double e00 = (i00 & 1u) ? q0.y : q0.x;
    const double e01 = (i01 & 1u) ? q1.y : q1.x;
    const double e02 = (i02 & 1u) ? q2.y : q2.x;
    const double e03 = (i03 & 1u) ? q3.y : q3.x;
    const double p00 = (i00 & 1u) ? q0.x : q0.y;
    const double p01 = (i01 & 1u) ? q1.x : q1.y;
    const double p02 = (i02 & 1u) ? q2.x : q2.y;
    const double p03 = (i03 & 1u) ? q3.x : q3.y;

    float2 f[8];
    f[0] = d2f2(e00); f[1] = d2f2(e01); f[2] = d2f2(e02); f[3] = d2f2(e03);
    f[4] = d2f2(odd ? g0 : p00);
    f[5] = d2f2(odd ? g1 : p01);
    f[6] = d2f2(odd ? g2 : p02);
    f[7] = d2f2(odd ? g3 : p03);

    const float wx0 = 1.0f - wx1;
    const float wy0 = 1.0f - wy1;
    const float wz0 = 1.0f - wz1;

    float a0 = 0.0f, a1 = 0.0f, w;
    w = wx0 * wy0 * wz0; a0 = fmaf(f[0].x, w, a0); a1 = fmaf(f[0].y, w, a1);
    w = wx0 * wy0 * wz1; a0 = fmaf(f[1].x, w, a0); a1 = fmaf(f[1].y, w, a1);
    w = wx0 * wy1 * wz0; a0 = fmaf(f[2].x, w, a0); a1 = fmaf(f[2].y, w, a1);
    w = wx0 * wy1 * wz1; a0 = fmaf(f[3].x, w, a0); a1 = fmaf(f[3].y, w, a1);
    w = wx1 * wy0 * wz0; a0 = fmaf(f[4].x, w, a0); a1 = fmaf(f[4].y, w, a1);
    w = wx1 * wy0 * wz1; a0 = fmaf(f[5].x, w, a0); a1 = fmaf(f[5].y, w, a1);
    w = wx1 * wy1 * wz0; a0 = fmaf(f[6].x, w, a0); a1 = fmaf(f[6].y, w, a1);
    w = wx1 * wy1 * wz1; a0 = fmaf(f[7].x, w, a0); a1 = fmaf(f[7].y, w, a1);

    __builtin_nontemporal_store(f22d(make_float2(a0, a1)),
                                &ws[(size_t)l * BATCH + p]);
}

__device__ __forceinline__ uint32_t wave_grab(uint32_t* ctr, int lane) {
    uint32_t c = 0;
    if (lane == 0) c = atomicAdd(ctr, 1u);
    return (uint32_t)__shfl((int)c, 0);
}

// Persistent-block phase A. 2048 blocks (256/XCD); each wave grabs 64-point
// units: first from its XCD's pinned fine-level queue, then from the coarse
// pools (own pool first, then steal). Grab-ahead pipelines the atomic.
__global__ __launch_bounds__(256) void enc_dyn_kernel(
    const float* __restrict__ in,
    const float* __restrict__ table,
    double* __restrict__ ws,
    uint32_t* __restrict__ ctr)        // 16 counters, 32-uint (128B) stride
{
    const int slot = blockIdx.x & 7;   // -> XCD
    const int lane = threadIdx.x & 63;

    // --- pinned fine-level phase ---
    {
        uint32_t* pc = ctr + slot * 32;
        const Seg s0 = c_pinned[slot][0];
        const Seg s1 = c_pinned[slot][1];
        uint32_t c = wave_grab(pc, lane);
        while (c < PINNED_TOTAL) {
            const uint32_t cn = wave_grab(pc, lane);   // grab-ahead
            int level, unit;
            if ((int)c < s0.count) { level = s0.level; unit = s0.base + (int)c; }
            else                   { level = s1.level; unit = s1.base + (int)c - s0.count; }
            process_unit(level, unit, lane, in, table, ws);
            c = cn;
        }
    }

    // --- shared coarse pools (l5 first = most expensive), with stealing ---
    for (int k = 0; k < 8; ++k) {
        const int pool = (slot + k) & 7;
        uint32_t* pc = ctr + (8 + pool) * 32;
        uint32_t c = wave_grab(pc, lane);
        while (c < COARSE_POOL) {
            const uint32_t cn = wave_grab(pc, lane);
            const int level = 5 - (int)(c >> 10);
            const int unit = (int)(c & 1023) + (pool << 10);
            process_unit(level, unit, lane, in, table, ws);
            c = cn;
        }
    }
}

__global__ __launch_bounds__(64) void init_ctr_kernel(uint32_t* ctr) {
    if (threadIdx.x < 16) ctr[threadIdx.x * 32] = 0u;
}

// Phase B: LDS-tiled transpose [L,B] -> [B,L]. Block stages 256 points x 16
// levels (dense 2KB reads per level), writes 256x128B coalesced.
__global__ __launch_bounds__(256) void transpose_kernel(
    const double* __restrict__ ws,     // [L, B] float2 as double
    nfloat4* __restrict__ out)         // [B*8]
{
    __shared__ double lds[256][NUM_LEVELS + 1];   // +1 pad

    const int tid = threadIdx.x;
    const int p0 = blockIdx.x * 256;

#pragma unroll
    for (int l = 0; l < NUM_LEVELS; ++l) {
        lds[tid][l] = __builtin_nontemporal_load(&ws[(size_t)l * BATCH + p0 + tid]);
    }
    __syncthreads();

#pragma unroll
    for (int it = 0; it < 8; ++it) {
        const int e = it * 256 + tid;
        const int p = e >> 3;
        const int j = e & 7;
        const float2 a = d2f2(lds[p][2 * j]);
        const float2 b = d2f2(lds[p][2 * j + 1]);
        nfloat4 r;
        r.x = a.x; r.y = a.y; r.z = b.x; r.w = b.y;
        __builtin_nontemporal_store(r, &out[(size_t)blockIdx.x * 2048 + e]);
    }
}

// Fallback: direct scatter store (no workspace needed).
struct Corner8 {
    uint32_t i[8];
    float wx0, wy0, wz0;
};

__device__ __forceinline__ Corner8 corner_setup_xyz(
    float xs, float ys, float zs, float n)
{
    const float tx = xs * n, ty = ys * n, tz = zs * n;
    const float fpx = floorf(tx), fpy = floorf(ty), fpz = floorf(tz);

    Corner8 c;
    c.wx0 = tx - fpx;
    c.wy0 = ty - fpy;
    c.wz0 = tz - fpz;

    const uint32_t px = (uint32_t)fpx;
    const uint32_t py = (uint32_t)fpy;
    const uint32_t pz = (uint32_t)fpz;

    const uint32_t hx0 = px;
    const uint32_t hx1 = px + 1u;
    const uint32_t hy0 = py * PRIME_Y;
    const uint32_t hy1 = hy0 + PRIME_Y;
    const uint32_t hz0 = pz * PRIME_Z;
    const uint32_t hz1 = hz0 + PRIME_Z;

    c.i[0] = (hx0 ^ hy0 ^ hz0) & TBL_MASK;
    c.i[1] = (hx0 ^ hy0 ^ hz1) & TBL_MASK;
    c.i[2] = (hx0 ^ hy1 ^ hz0) & TBL_MASK;
    c.i[3] = (hx0 ^ hy1 ^ hz1) & TBL_MASK;
    c.i[4] = (hx1 ^ hy0 ^ hz0) & TBL_MASK;
    c.i[5] = (hx1 ^ hy0 ^ hz1) & TBL_MASK;
    c.i[6] = (hx1 ^ hy1 ^ hz0) & TBL_MASK;
    c.i[7] = (hx1 ^ hy1 ^ hz1) & TBL_MASK;
    return c;
}

__device__ __forceinline__ float2 blend8(const Corner8& c, const float2 f[8])
{
    const float wx1 = c.wx0, wx0 = 1.0f - c.wx0;
    const float wy1 = c.wy0, wy0 = 1.0f - c.wy0;
    const float wz1 = c.wz0, wz0 = 1.0f - c.wz0;

    float a0 = 0.0f, a1 = 0.0f, w;
    w = wx0 * wy0 * wz0; a0 = fmaf(f[0].x, w, a0); a1 = fmaf(f[0].y, w, a1);
    w = wx0 * wy0 * wz1; a0 = fmaf(f[1].x, w, a0); a1 = fmaf(f[1].y, w, a1);
    w = wx0 * wy1 * wz0; a0 = fmaf(f[2].x, w, a0); a1 = fmaf(f[2].y, w, a1);
    w = wx0 * wy1 * wz1; a0 = fmaf(f[3].x, w, a0); a1 = fmaf(f[3].y, w, a1);
    w = wx1 * wy0 * wz0; a0 = fmaf(f[4].x, w, a0); a1 = fmaf(f[4].y, w, a1);
    w = wx1 * wy0 * wz1; a0 = fmaf(f[5].x, w, a0); a1 = fmaf(f[5].y, w, a1);
    w = wx1 * wy1 * wz0; a0 = fmaf(f[6].x, w, a0); a1 = fmaf(f[6].y, w, a1);
    w = wx1 * wy1 * wz1; a0 = fmaf(f[7].x, w, a0); a1 = fmaf(f[7].y, w, a1);
    return make_float2(a0, a1);
}

__global__ __launch_bounds__(256) void enc_scatter_kernel(
    const float* __restrict__ in,
    const float* __restrict__ table,
    float2* __restrict__ out)          // [B, 16] float2
{
    const int v = blockIdx.x & 15;
    const int chunk = blockIdx.x >> 4;
    const int l = (v < 8) ? (15 - v) : (v - 8);
    const int p = chunk * 256 + threadIdx.x;

    const float vx = in[p * 3 + 0];
    const float vy = in[p * 3 + 1];
    const float vz = in[p * 3 + 2];
    const Corner8 c = corner_setup_xyz((vx + 3.0f) / 6.0f, (vy + 3.0f) / 6.0f,
                                       (vz + 3.0f) / 6.0f, c_ns[l]);
    const double* __restrict__ tb = ((const double*)table) + ((size_t)l << 19);
    float2 f[8];
#pragma unroll
    for (int k = 0; k < 8; ++k) f[k] = d2f2(tb[c.i[k]]);
    out[(size_t)p * NUM_LEVELS + l] = blend8(c, f);
}

extern "C" void kernel_launch(void* const* d_in, const int* in_sizes, int n_in,
                              void* d_out, int out_size, void* d_ws, size_t ws_size,
                              hipStream_t stream) {
    const float* inputs = (const float*)d_in[0];   // [B,3] fp32
    const float* table  = (const float*)d_in[1];   // [16, 2^19, 2] fp32

    const size_t ws_needed = (size_t)NUM_LEVELS * BATCH * sizeof(float2); // 64 MiB

    if (ws_size >= ws_needed) {
        double* ws = (double*)d_ws;
        uint32_t* ctr = (uint32_t*)d_out;   // first 2KB of out as counters;
                                            // transpose overwrites afterwards
        init_ctr_kernel<<<1, 64, 0, stream>>>(ctr);
        // Phase A: persistent blocks, 256 per XCD (8 per CU).
        enc_dyn_kernel<<<2048, 256, 0, stream>>>(inputs, table, ws, ctr);
        // Phase B: 524288/256 = 2048 blocks.
        transpose_kernel<<<2048, 256, 0, stream>>>(ws, (nfloat4*)d_out);
    } else {
        enc_scatter_kernel<<<32768, 256, 0, stream>>>(inputs, table, (float2*)d_out);
    }
}

// Round 3
// 351.420 us; speedup vs baseline: 1.5481x; 1.5481x over previous
//
#include <hip/hip_runtime.h>
#include <cstdint>
#include <cstddef>

// PositionalEncoderGrid: Instant-NGP multiresolution hash grid.
// B=524288 points, L=16 levels, T=2^19 entries/level, F=2 floats.
//
// R10: R8 structure EXACTLY (two static passes, one level per XCD per pass,
//      cached table loads, nt input/ws streaming) + the x-pair gather trick
//      from R9, now isolated:
//        corners (x0,c) and (x1,c) satisfy i_x1 == i_x0 ^ 1 when px is even
//        (px+1 flips only bit 0; XOR with the hash and the pow2 mask commute
//        with bit 0), and {i&~1, i|1} is one aligned 16B pair -> a single
//        dwordx4 covers both corners. Odd-px lanes issue 4 extra masked
//        gathers. Distinct 64B segments per point: 8 -> 6 expected.
//      R9 bundled this with a dynamic schedule that thrashed L2 (FETCH
//      129->265 MB) and masked the effect. This round isolates it.

#define NUM_LEVELS 16
#define TBL_MASK ((1u << 19) - 1u)
#define PRIME_Y 2654435761u
#define PRIME_Z 805459861u
#define BATCH 524288

typedef float nfloat4 __attribute__((ext_vector_type(4)));
typedef double ndouble2 __attribute__((ext_vector_type(2)));

__constant__ float c_ns[NUM_LEVELS] = {
    16.f, 20.f, 25.f, 32.f, 40.f, 50.f, 64.f, 80.f,
    101.f, 128.f, 161.f, 203.f, 256.f, 322.f, 406.f, 512.f
};

__device__ __forceinline__ float2 d2f2(double d) {
    union { double d; float2 f; } u;
    u.d = d;
    return u.f;
}

__device__ __forceinline__ double f22d(float2 f) {
    union { double d; float2 f; } u;
    u.f = f;
    return u.d;
}

// Phase A: each block handles 256 points for ONE level; level = base + XCD
// slot, so each XCD's L2 holds exactly one level's table for the whole pass.
__global__ __launch_bounds__(256) void enc_level_kernel(
    const float* __restrict__ in,
    const float* __restrict__ table,
    double* __restrict__ ws,           // [L, B] float2 as double
    int base_level)
{
    const int slot = blockIdx.x & 7;           // -> XCD slot
    const int chunk = blockIdx.x >> 3;         // 2048 chunks of 256 points
    const int l = base_level + slot;
    const int p = chunk * 256 + threadIdx.x;

    // Streaming input: nt so it doesn't evict the L2-resident table.
    const float vx = __builtin_nontemporal_load(&in[p * 3 + 0]);
    const float vy = __builtin_nontemporal_load(&in[p * 3 + 1]);
    const float vz = __builtin_nontemporal_load(&in[p * 3 + 2]);
    const float xs = (vx + 3.0f) / 6.0f;
    const float ys = (vy + 3.0f) / 6.0f;
    const float zs = (vz + 3.0f) / 6.0f;

    const float n = c_ns[l];
    const float tx = xs * n, ty = ys * n, tz = zs * n;
    const float fpx = floorf(tx), fpy = floorf(ty), fpz = floorf(tz);
    const float wx1 = tx - fpx, wy1 = ty - fpy, wz1 = tz - fpz;
    const uint32_t px = (uint32_t)fpx;
    const uint32_t py = (uint32_t)fpy;
    const uint32_t pz = (uint32_t)fpz;

    const uint32_t hy0 = py * PRIME_Y, hy1 = hy0 + PRIME_Y;
    const uint32_t hz0 = pz * PRIME_Z, hz1 = hz0 + PRIME_Z;
    const uint32_t b0 = hy0 ^ hz0, b1 = hy0 ^ hz1;
    const uint32_t b2 = hy1 ^ hz0, b3 = hy1 ^ hz1;

    const uint32_t i00 = (px ^ b0) & TBL_MASK;
    const uint32_t i01 = (px ^ b1) & TBL_MASK;
    const uint32_t i02 = (px ^ b2) & TBL_MASK;
    const uint32_t i03 = (px ^ b3) & TBL_MASK;
    const uint32_t qx = px + 1u;
    const uint32_t i40 = (qx ^ b0) & TBL_MASK;
    const uint32_t i41 = (qx ^ b1) & TBL_MASK;
    const uint32_t i42 = (qx ^ b2) & TBL_MASK;
    const uint32_t i43 = (qx ^ b3) & TBL_MASK;

    const double* __restrict__ tb = ((const double*)table) + ((size_t)l << 19);
    const ndouble2* __restrict__ tb2 = (const ndouble2*)tb;

    // x0 corners via aligned 16B pair loads; for even px the same pair also
    // contains the x1 partner (i4 == i0^1). CACHED loads -- the per-XCD
    // level pinning keeps these L2-resident.
    const ndouble2 q0 = tb2[i00 >> 1];
    const ndouble2 q1 = tb2[i01 >> 1];
    const ndouble2 q2 = tb2[i02 >> 1];
    const ndouble2 q3 = tb2[i03 >> 1];

    const bool odd = (px & 1u) != 0u;
    double g0 = 0.0, g1 = 0.0, g2 = 0.0, g3 = 0.0;
    if (odd) {   // divergent: only odd-px lanes issue these 4 gathers
        g0 = tb[i40];
        g1 = tb[i41];
        g2 = tb[i42];
        g3 = tb[i43];
    }

    const double e00 = (i00 & 1u) ? q0.y : q0.x;
    const double e01 = (i01 & 1u) ? q1.y : q1.x;
    const double e02 = (i02 & 1u) ? q2.y : q2.x;
    const double e03 = (i03 & 1u) ? q3.y : q3.x;
    const double p00 = (i00 & 1u) ? q0.x : q0.y;
    const double p01 = (i01 & 1u) ? q1.x : q1.y;
    const double p02 = (i02 & 1u) ? q2.x : q2.y;
    const double p03 = (i03 & 1u) ? q3.x : q3.y;

    float2 f[8];
    f[0] = d2f2(e00); f[1] = d2f2(e01); f[2] = d2f2(e02); f[3] = d2f2(e03);
    f[4] = d2f2(odd ? g0 : p00);
    f[5] = d2f2(odd ? g1 : p01);
    f[6] = d2f2(odd ? g2 : p02);
    f[7] = d2f2(odd ? g3 : p03);

    const float wx0 = 1.0f - wx1;
    const float wy0 = 1.0f - wy1;
    const float wz0 = 1.0f - wz1;

    float a0 = 0.0f, a1 = 0.0f, w;
    w = wx0 * wy0 * wz0; a0 = fmaf(f[0].x, w, a0); a1 = fmaf(f[0].y, w, a1);
    w = wx0 * wy0 * wz1; a0 = fmaf(f[1].x, w, a0); a1 = fmaf(f[1].y, w, a1);
    w = wx0 * wy1 * wz0; a0 = fmaf(f[2].x, w, a0); a1 = fmaf(f[2].y, w, a1);
    w = wx0 * wy1 * wz1; a0 = fmaf(f[3].x, w, a0); a1 = fmaf(f[3].y, w, a1);
    w = wx1 * wy0 * wz0; a0 = fmaf(f[4].x, w, a0); a1 = fmaf(f[4].y, w, a1);
    w = wx1 * wy0 * wz1; a0 = fmaf(f[5].x, w, a0); a1 = fmaf(f[5].y, w, a1);
    w = wx1 * wy1 * wz0; a0 = fmaf(f[6].x, w, a0); a1 = fmaf(f[6].y, w, a1);
    w = wx1 * wy1 * wz1; a0 = fmaf(f[7].x, w, a0); a1 = fmaf(f[7].y, w, a1);

    __builtin_nontemporal_store(f22d(make_float2(a0, a1)),
                                &ws[(size_t)l * BATCH + p]);
}

// Phase B: LDS-tiled transpose [L,B] -> [B,L]. Block stages 256 points x 16
// levels (dense 2KB reads per level), writes 256x128B coalesced.
__global__ __launch_bounds__(256) void transpose_kernel(
    const double* __restrict__ ws,     // [L, B] float2 as double
    nfloat4* __restrict__ out)         // [B*8]
{
    __shared__ double lds[256][NUM_LEVELS + 1];   // +1 pad: 34B-row stride

    const int tid = threadIdx.x;
    const int p0 = blockIdx.x * 256;

#pragma unroll
    for (int l = 0; l < NUM_LEVELS; ++l) {
        lds[tid][l] = __builtin_nontemporal_load(&ws[(size_t)l * BATCH + p0 + tid]);
    }
    __syncthreads();

    // 2048 float4s per block; lane-contiguous stores.
#pragma unroll
    for (int it = 0; it < 8; ++it) {
        const int e = it * 256 + tid;
        const int p = e >> 3;          // point within tile
        const int j = e & 7;           // float4 index within point
        const float2 a = d2f2(lds[p][2 * j]);
        const float2 b = d2f2(lds[p][2 * j + 1]);
        nfloat4 r;
        r.x = a.x; r.y = a.y; r.z = b.x; r.w = b.y;
        __builtin_nontemporal_store(r, &out[(size_t)blockIdx.x * 2048 + e]);
    }
}

// Fallback: direct scatter store (no workspace needed).
struct Corner8 {
    uint32_t i[8];
    float wx0, wy0, wz0;
};

__device__ __forceinline__ Corner8 corner_setup_xyz(
    float xs, float ys, float zs, float n)
{
    const float tx = xs * n, ty = ys * n, tz = zs * n;
    const float fpx = floorf(tx), fpy = floorf(ty), fpz = floorf(tz);

    Corner8 c;
    c.wx0 = tx - fpx;
    c.wy0 = ty - fpy;
    c.wz0 = tz - fpz;

    const uint32_t px = (uint32_t)fpx;
    const uint32_t py = (uint32_t)fpy;
    const uint32_t pz = (uint32_t)fpz;

    const uint32_t hx0 = px;
    const uint32_t hx1 = px + 1u;
    const uint32_t hy0 = py * PRIME_Y;
    const uint32_t hy1 = hy0 + PRIME_Y;
    const uint32_t hz0 = pz * PRIME_Z;
    const uint32_t hz1 = hz0 + PRIME_Z;

    c.i[0] = (hx0 ^ hy0 ^ hz0) & TBL_MASK;
    c.i[1] = (hx0 ^ hy0 ^ hz1) & TBL_MASK;
    c.i[2] = (hx0 ^ hy1 ^ hz0) & TBL_MASK;
    c.i[3] = (hx0 ^ hy1 ^ hz1) & TBL_MASK;
    c.i[4] = (hx1 ^ hy0 ^ hz0) & TBL_MASK;
    c.i[5] = (hx1 ^ hy0 ^ hz1) & TBL_MASK;
    c.i[6] = (hx1 ^ hy1 ^ hz0) & TBL_MASK;
    c.i[7] = (hx1 ^ hy1 ^ hz1) & TBL_MASK;
    return c;
}

__device__ __forceinline__ float2 blend8(const Corner8& c, const float2 f[8])
{
    const float wx1 = c.wx0, wx0 = 1.0f - c.wx0;
    const float wy1 = c.wy0, wy0 = 1.0f - c.wy0;
    const float wz1 = c.wz0, wz0 = 1.0f - c.wz0;

    float a0 = 0.0f, a1 = 0.0f, w;
    w = wx0 * wy0 * wz0; a0 = fmaf(f[0].x, w, a0); a1 = fmaf(f[0].y, w, a1);
    w = wx0 * wy0 * wz1; a0 = fmaf(f[1].x, w, a0); a1 = fmaf(f[1].y, w, a1);
    w = wx0 * wy1 * wz0; a0 = fmaf(f[2].x, w, a0); a1 = fmaf(f[2].y, w, a1);
    w = wx0 * wy1 * wz1; a0 = fmaf(f[3].x, w, a0); a1 = fmaf(f[3].y, w, a1);
    w = wx1 * wy0 * wz0; a0 = fmaf(f[4].x, w, a0); a1 = fmaf(f[4].y, w, a1);
    w = wx1 * wy0 * wz1; a0 = fmaf(f[5].x, w, a0); a1 = fmaf(f[5].y, w, a1);
    w = wx1 * wy1 * wz0; a0 = fmaf(f[6].x, w, a0); a1 = fmaf(f[6].y, w, a1);
    w = wx1 * wy1 * wz1; a0 = fmaf(f[7].x, w, a0); a1 = fmaf(f[7].y, w, a1);
    return make_float2(a0, a1);
}

__global__ __launch_bounds__(256) void enc_scatter_kernel(
    const float* __restrict__ in,
    const float* __restrict__ table,
    float2* __restrict__ out)          // [B, 16] float2
{
    const int v = blockIdx.x & 15;
    const int chunk = blockIdx.x >> 4;
    const int l = (v < 8) ? (15 - v) : (v - 8);
    const int p = chunk * 256 + threadIdx.x;

    const float vx = in[p * 3 + 0];
    const float vy = in[p * 3 + 1];
    const float vz = in[p * 3 + 2];
    const Corner8 c = corner_setup_xyz((vx + 3.0f) / 6.0f, (vy + 3.0f) / 6.0f,
                                       (vz + 3.0f) / 6.0f, c_ns[l]);
    const double* __restrict__ tb = ((const double*)table) + ((size_t)l << 19);
    float2 f[8];
#pragma unroll
    for (int k = 0; k < 8; ++k) f[k] = d2f2(tb[c.i[k]]);
    out[(size_t)p * NUM_LEVELS + l] = blend8(c, f);
}

extern "C" void kernel_launch(void* const* d_in, const int* in_sizes, int n_in,
                              void* d_out, int out_size, void* d_ws, size_t ws_size,
                              hipStream_t stream) {
    const float* inputs = (const float*)d_in[0];   // [B,3] fp32
    const float* table  = (const float*)d_in[1];   // [16, 2^19, 2] fp32

    const size_t ws_needed = (size_t)NUM_LEVELS * BATCH * sizeof(float2); // 64 MiB

    if (ws_size >= ws_needed) {
        double* ws = (double*)d_ws;
        // Phase A pass 1: levels 8-15, one level per XCD (4 MiB table == L2).
        enc_level_kernel<<<16384, 256, 0, stream>>>(inputs, table, ws, 8);
        // Phase A pass 2: levels 0-7 (footprints 0.3-4 MiB, all fit L2).
        enc_level_kernel<<<16384, 256, 0, stream>>>(inputs, table, ws, 0);
        // Phase B: 524288/256 = 2048 blocks.
        transpose_kernel<<<2048, 256, 0, stream>>>(ws, (nfloat4*)d_out);
    } else {
        enc_scatter_kernel<<<32768, 256, 0, stream>>>(inputs, table, (float2*)d_out);
    }
}

// Round 4
// 349.171 us; speedup vs baseline: 1.5580x; 1.0064x over previous
//
#include <hip/hip_runtime.h>
#include <cstdint>
#include <cstddef>

// PositionalEncoderGrid: Instant-NGP multiresolution hash grid.
// B=524288 points, L=16 levels, T=2^19 entries/level, F=2 floats.
//
// R11: confirmed model: phase A is bound by active-lane gather requests at
//      ~3.1 cyc/request/CU (R8 8req->161us, R10 6req->128us). Three changes,
//      each in its OWN dispatch for counter attribution:
//      1) coarse_kernel: l0/l1 served from LDS. Cell footprint l0=18^3
//         (46.7KiB), l1=22^3 (85.2KiB) fits LDS; block gathers the hashed
//         cube once (5832/10648 requests) then all 8 corner lookups are
//         ds_read_b64. Removes 2/16 of global-gather work.
//      2) enc_sched pass 2 rebalanced: l2..l7 (6 levels) split fractionally
//         over 8 XCDs, level-major contiguous per XCD (<=2 tables,
//         SEQUENTIAL -- the static fix for R9's dynamic-schedule thrash).
//         Pass-2 makespan 128 -> ~96us.
//      3) ws goes chunk-major [B/256][16][256]float2: enc stores stay 512B/
//         wave coalesced; transpose now reads one contiguous 32KiB block per
//         chunk (was 16 streams 4MiB apart) -> pure stream traffic.

#define NUM_LEVELS 16
#define TBL_MASK ((1u << 19) - 1u)
#define PRIME_Y 2654435761u
#define PRIME_Z 805459861u
#define BATCH 524288

typedef float nfloat4 __attribute__((ext_vector_type(4)));
typedef double ndouble2 __attribute__((ext_vector_type(2)));

__constant__ float c_ns[NUM_LEVELS] = {
    16.f, 20.f, 25.f, 32.f, 40.f, 50.f, 64.f, 80.f,
    101.f, 128.f, 161.f, 203.f, 256.f, 322.f, 406.f, 512.f
};

__device__ __forceinline__ float2 d2f2(double d) {
    union { double d; float2 f; } u;
    u.d = d;
    return u.f;
}

__device__ __forceinline__ double f22d(float2 f) {
    union { double d; float2 f; } u;
    u.f = f;
    return u.d;
}

// chunk-major ws index (float2/double units): [p>>8][l][p&255]
__device__ __forceinline__ size_t ws_idx(int p, int l) {
    return ((size_t)(p >> 8) * NUM_LEVELS + l) * 256 + (p & 255);
}

// Phase A fine levels: level-major contiguous static schedule per XCD.
// g = slot*cps + seq; level = base + g/2048; chunk-in-level = g%2048.
// Per XCD, seq increases with launch order -> one table at a time in L2
// (<=2 tables, sequential, at fractional boundaries).
__global__ __launch_bounds__(256) void enc_sched_kernel(
    const float* __restrict__ in,
    const float* __restrict__ table,
    double* __restrict__ ws,
    int base_level, int cps)
{
    const int slot = blockIdx.x & 7;           // -> XCD
    const int seq  = blockIdx.x >> 3;
    const int g = slot * cps + seq;
    const int l = base_level + (g >> 11);      // 2048 chunks per level
    const int cil = g & 2047;
    const int p = cil * 256 + threadIdx.x;

    // Streaming input: nt so it doesn't evict the L2-resident table.
    const float vx = __builtin_nontemporal_load(&in[p * 3 + 0]);
    const float vy = __builtin_nontemporal_load(&in[p * 3 + 1]);
    const float vz = __builtin_nontemporal_load(&in[p * 3 + 2]);
    const float xs = (vx + 3.0f) / 6.0f;
    const float ys = (vy + 3.0f) / 6.0f;
    const float zs = (vz + 3.0f) / 6.0f;

    const float n = c_ns[l];
    const float tx = xs * n, ty = ys * n, tz = zs * n;
    const float fpx = floorf(tx), fpy = floorf(ty), fpz = floorf(tz);
    const float wx1 = tx - fpx, wy1 = ty - fpy, wz1 = tz - fpz;
    const uint32_t px = (uint32_t)fpx;
    const uint32_t py = (uint32_t)fpy;
    const uint32_t pz = (uint32_t)fpz;

    const uint32_t hy0 = py * PRIME_Y, hy1 = hy0 + PRIME_Y;
    const uint32_t hz0 = pz * PRIME_Z, hz1 = hz0 + PRIME_Z;
    const uint32_t b0 = hy0 ^ hz0, b1 = hy0 ^ hz1;
    const uint32_t b2 = hy1 ^ hz0, b3 = hy1 ^ hz1;

    const uint32_t i00 = (px ^ b0) & TBL_MASK;
    const uint32_t i01 = (px ^ b1) & TBL_MASK;
    const uint32_t i02 = (px ^ b2) & TBL_MASK;
    const uint32_t i03 = (px ^ b3) & TBL_MASK;
    const uint32_t qx = px + 1u;
    const uint32_t i40 = (qx ^ b0) & TBL_MASK;
    const uint32_t i41 = (qx ^ b1) & TBL_MASK;
    const uint32_t i42 = (qx ^ b2) & TBL_MASK;
    const uint32_t i43 = (qx ^ b3) & TBL_MASK;

    const double* __restrict__ tb = ((const double*)table) + ((size_t)l << 19);
    const ndouble2* __restrict__ tb2 = (const ndouble2*)tb;

    // x-pair trick: for even px the aligned 16B pair {i&~1, i|1} holds both
    // x-corners (i_x1 == i_x0 ^ 1). CACHED loads (L2-pinned table).
    const ndouble2 q0 = tb2[i00 >> 1];
    const ndouble2 q1 = tb2[i01 >> 1];
    const ndouble2 q2 = tb2[i02 >> 1];
    const ndouble2 q3 = tb2[i03 >> 1];

    const bool odd = (px & 1u) != 0u;
    double g0 = 0.0, g1 = 0.0, g2 = 0.0, g3 = 0.0;
    if (odd) {   // divergent: only odd-px lanes issue these 4 gathers
        g0 = tb[i40];
        g1 = tb[i41];
        g2 = tb[i42];
        g3 = tb[i43];
    }

    const double e00 = (i00 & 1u) ? q0.y : q0.x;
    const double e01 = (i01 & 1u) ? q1.y : q1.x;
    const double e02 = (i02 & 1u) ? q2.y : q2.x;
    const double e03 = (i03 & 1u) ? q3.y : q3.x;
    const double p00 = (i00 & 1u) ? q0.x : q0.y;
    const double p01 = (i01 & 1u) ? q1.x : q1.y;
    const double p02 = (i02 & 1u) ? q2.x : q2.y;
    const double p03 = (i03 & 1u) ? q3.x : q3.y;

    float2 f[8];
    f[0] = d2f2(e00); f[1] = d2f2(e01); f[2] = d2f2(e02); f[3] = d2f2(e03);
    f[4] = d2f2(odd ? g0 : p00);
    f[5] = d2f2(odd ? g1 : p01);
    f[6] = d2f2(odd ? g2 : p02);
    f[7] = d2f2(odd ? g3 : p03);

    const float wx0 = 1.0f - wx1;
    const float wy0 = 1.0f - wy1;
    const float wz0 = 1.0f - wz1;

    float a0 = 0.0f, a1 = 0.0f, w;
    w = wx0 * wy0 * wz0; a0 = fmaf(f[0].x, w, a0); a1 = fmaf(f[0].y, w, a1);
    w = wx0 * wy0 * wz1; a0 = fmaf(f[1].x, w, a0); a1 = fmaf(f[1].y, w, a1);
    w = wx0 * wy1 * wz0; a0 = fmaf(f[2].x, w, a0); a1 = fmaf(f[2].y, w, a1);
    w = wx0 * wy1 * wz1; a0 = fmaf(f[3].x, w, a0); a1 = fmaf(f[3].y, w, a1);
    w = wx1 * wy0 * wz0; a0 = fmaf(f[4].x, w, a0); a1 = fmaf(f[4].y, w, a1);
    w = wx1 * wy0 * wz1; a0 = fmaf(f[5].x, w, a0); a1 = fmaf(f[5].y, w, a1);
    w = wx1 * wy1 * wz0; a0 = fmaf(f[6].x, w, a0); a1 = fmaf(f[6].y, w, a1);
    w = wx1 * wy1 * wz1; a0 = fmaf(f[7].x, w, a0); a1 = fmaf(f[7].y, w, a1);

    __builtin_nontemporal_store(f22d(make_float2(a0, a1)), &ws[ws_idx(p, l)]);
}

// Coarse levels l0/l1: stage the full hashed cell cube in LDS (one gather
// per CELL instead of 6-8 per POINT), then per-point lookups are ds_read.
// d = n+2 covers px+1 with margin. 256 blocks x 1024 thr; 4096 pts/block.
template <int LVL, int D>
__device__ __forceinline__ void coarse_body(
    const float* __restrict__ in,
    const float* __restrict__ table,
    double* __restrict__ ws,
    double* __restrict__ cache,
    int part)
{
    const int tid = threadIdx.x;
    const double* __restrict__ tb =
        ((const double*)table) + ((size_t)LVL << 19);

    // Stage cube: cell c -> (cx,cy,cz), gather T[hash].
    for (int c = tid; c < D * D * D; c += 1024) {
        const uint32_t cz = (uint32_t)(c % D);
        const uint32_t r  = (uint32_t)(c / D);
        const uint32_t cy = r % D;
        const uint32_t cx = r / D;
        const uint32_t h = (cx ^ (cy * PRIME_Y) ^ (cz * PRIME_Z)) & TBL_MASK;
        cache[c] = tb[h];
    }
    __syncthreads();

    const float n = c_ns[LVL];
#pragma unroll
    for (int it = 0; it < 4; ++it) {
        const int p = part * 4096 + it * 1024 + tid;
        const float vx = __builtin_nontemporal_load(&in[p * 3 + 0]);
        const float vy = __builtin_nontemporal_load(&in[p * 3 + 1]);
        const float vz = __builtin_nontemporal_load(&in[p * 3 + 2]);
        const float xs = (vx + 3.0f) / 6.0f;
        const float ys = (vy + 3.0f) / 6.0f;
        const float zs = (vz + 3.0f) / 6.0f;
        const float tx = xs * n, ty = ys * n, tz = zs * n;
        const float fpx = floorf(tx), fpy = floorf(ty), fpz = floorf(tz);
        const float wx1 = tx - fpx, wy1 = ty - fpy, wz1 = tz - fpz;
        const int px = (int)fpx, py = (int)fpy, pz = (int)fpz;

        const int base = (px * D + py) * D + pz;
        float2 f[8];
        f[0] = d2f2(cache[base]);
        f[1] = d2f2(cache[base + 1]);
        f[2] = d2f2(cache[base + D]);
        f[3] = d2f2(cache[base + D + 1]);
        f[4] = d2f2(cache[base + D * D]);
        f[5] = d2f2(cache[base + D * D + 1]);
        f[6] = d2f2(cache[base + D * D + D]);
        f[7] = d2f2(cache[base + D * D + D + 1]);

        const float wx0 = 1.0f - wx1;
        const float wy0 = 1.0f - wy1;
        const float wz0 = 1.0f - wz1;

        float a0 = 0.0f, a1 = 0.0f, w;
        w = wx0 * wy0 * wz0; a0 = fmaf(f[0].x, w, a0); a1 = fmaf(f[0].y, w, a1);
        w = wx0 * wy0 * wz1; a0 = fmaf(f[1].x, w, a0); a1 = fmaf(f[1].y, w, a1);
        w = wx0 * wy1 * wz0; a0 = fmaf(f[2].x, w, a0); a1 = fmaf(f[2].y, w, a1);
        w = wx0 * wy1 * wz1; a0 = fmaf(f[3].x, w, a0); a1 = fmaf(f[3].y, w, a1);
        w = wx1 * wy0 * wz0; a0 = fmaf(f[4].x, w, a0); a1 = fmaf(f[4].y, w, a1);
        w = wx1 * wy0 * wz1; a0 = fmaf(f[5].x, w, a0); a1 = fmaf(f[5].y, w, a1);
        w = wx1 * wy1 * wz0; a0 = fmaf(f[6].x, w, a0); a1 = fmaf(f[6].y, w, a1);
        w = wx1 * wy1 * wz1; a0 = fmaf(f[7].x, w, a0); a1 = fmaf(f[7].y, w, a1);

        __builtin_nontemporal_store(f22d(make_float2(a0, a1)),
                                    &ws[ws_idx(p, LVL)]);
    }
}

__global__ __launch_bounds__(1024) void coarse_kernel(
    const float* __restrict__ in,
    const float* __restrict__ table,
    double* __restrict__ ws)
{
    extern __shared__ double cache[];          // 22^3 doubles = 85,184 B
    const int part = blockIdx.x & 127;         // 128 parts x 4096 pts
    if ((blockIdx.x >> 7) == 0) coarse_body<0, 18>(in, table, ws, cache, part);
    else                        coarse_body<1, 22>(in, table, ws, cache, part);
}

// Phase B: chunk-major ws -> [B,L] out. Block reads one contiguous 32KiB
// chunk ([16][256] f2), LDS-transposes, writes 32KiB contiguous.
__global__ __launch_bounds__(256) void transpose_kernel(
    const double* __restrict__ ws,
    nfloat4* __restrict__ out)                 // [B*8]
{
    __shared__ double lds[256][NUM_LEVELS + 1];   // +1 pad

    const int tid = threadIdx.x;
    const size_t base = (size_t)blockIdx.x * (NUM_LEVELS * 256);

#pragma unroll
    for (int l = 0; l < NUM_LEVELS; ++l) {
        lds[tid][l] = ws[base + (size_t)l * 256 + tid];
    }
    __syncthreads();

#pragma unroll
    for (int it = 0; it < 8; ++it) {
        const int e = it * 256 + tid;
        const int p = e >> 3;          // point within tile
        const int j = e & 7;           // float4 index within point
        const float2 a = d2f2(lds[p][2 * j]);
        const float2 b = d2f2(lds[p][2 * j + 1]);
        nfloat4 r;
        r.x = a.x; r.y = a.y; r.z = b.x; r.w = b.y;
        __builtin_nontemporal_store(r, &out[(size_t)blockIdx.x * 2048 + e]);
    }
}

// Fallback: direct scatter store (no workspace needed).
struct Corner8 {
    uint32_t i[8];
    float wx0, wy0, wz0;
};

__device__ __forceinline__ Corner8 corner_setup_xyz(
    float xs, float ys, float zs, float n)
{
    const float tx = xs * n, ty = ys * n, tz = zs * n;
    const float fpx = floorf(tx), fpy = floorf(ty), fpz = floorf(tz);

    Corner8 c;
    c.wx0 = tx - fpx;
    c.wy0 = ty - fpy;
    c.wz0 = tz - fpz;

    const uint32_t px = (uint32_t)fpx;
    const uint32_t py = (uint32_t)fpy;
    const uint32_t pz = (uint32_t)fpz;

    const uint32_t hx0 = px;
    const uint32_t hx1 = px + 1u;
    const uint32_t hy0 = py * PRIME_Y;
    const uint32_t hy1 = hy0 + PRIME_Y;
    const uint32_t hz0 = pz * PRIME_Z;
    const uint32_t hz1 = hz0 + PRIME_Z;

    c.i[0] = (hx0 ^ hy0 ^ hz0) & TBL_MASK;
    c.i[1] = (hx0 ^ hy0 ^ hz1) & TBL_MASK;
    c.i[2] = (hx0 ^ hy1 ^ hz0) & TBL_MASK;
    c.i[3] = (hx0 ^ hy1 ^ hz1) & TBL_MASK;
    c.i[4] = (hx1 ^ hy0 ^ hz0) & TBL_MASK;
    c.i[5] = (hx1 ^ hy0 ^ hz1) & TBL_MASK;
    c.i[6] = (hx1 ^ hy1 ^ hz0) & TBL_MASK;
    c.i[7] = (hx1 ^ hy1 ^ hz1) & TBL_MASK;
    return c;
}

__device__ __forceinline__ float2 blend8(const Corner8& c, const float2 f[8])
{
    const float wx1 = c.wx0, wx0 = 1.0f - c.wx0;
    const float wy1 = c.wy0, wy0 = 1.0f - c.wy0;
    const float wz1 = c.wz0, wz0 = 1.0f - c.wz0;

    float a0 = 0.0f, a1 = 0.0f, w;
    w = wx0 * wy0 * wz0; a0 = fmaf(f[0].x, w, a0); a1 = fmaf(f[0].y, w, a1);
    w = wx0 * wy0 * wz1; a0 = fmaf(f[1].x, w, a0); a1 = fmaf(f[1].y, w, a1);
    w = wx0 * wy1 * wz0; a0 = fmaf(f[2].x, w, a0); a1 = fmaf(f[2].y, w, a1);
    w = wx0 * wy1 * wz1; a0 = fmaf(f[3].x, w, a0); a1 = fmaf(f[3].y, w, a1);
    w = wx1 * wy0 * wz0; a0 = fmaf(f[4].x, w, a0); a1 = fmaf(f[4].y, w, a1);
    w = wx1 * wy0 * wz1; a0 = fmaf(f[5].x, w, a0); a1 = fmaf(f[5].y, w, a1);
    w = wx1 * wy1 * wz0; a0 = fmaf(f[6].x, w, a0); a1 = fmaf(f[6].y, w, a1);
    w = wx1 * wy1 * wz1; a0 = fmaf(f[7].x, w, a0); a1 = fmaf(f[7].y, w, a1);
    return make_float2(a0, a1);
}

__global__ __launch_bounds__(256) void enc_scatter_kernel(
    const float* __restrict__ in,
    const float* __restrict__ table,
    float2* __restrict__ out)          // [B, 16] float2
{
    const int v = blockIdx.x & 15;
    const int chunk = blockIdx.x >> 4;
    const int l = (v < 8) ? (15 - v) : (v - 8);
    const int p = chunk * 256 + threadIdx.x;

    const float vx = in[p * 3 + 0];
    const float vy = in[p * 3 + 1];
    const float vz = in[p * 3 + 2];
    const Corner8 c = corner_setup_xyz((vx + 3.0f) / 6.0f, (vy + 3.0f) / 6.0f,
                                       (vz + 3.0f) / 6.0f, c_ns[l]);
    const double* __restrict__ tb = ((const double*)table) + ((size_t)l << 19);
    float2 f[8];
#pragma unroll
    for (int k = 0; k < 8; ++k) f[k] = d2f2(tb[c.i[k]]);
    out[(size_t)p * NUM_LEVELS + l] = blend8(c, f);
}

extern "C" void kernel_launch(void* const* d_in, const int* in_sizes, int n_in,
                              void* d_out, int out_size, void* d_ws, size_t ws_size,
                              hipStream_t stream) {
    const float* inputs = (const float*)d_in[0];   // [B,3] fp32
    const float* table  = (const float*)d_in[1];   // [16, 2^19, 2] fp32

    const size_t ws_needed = (size_t)NUM_LEVELS * BATCH * sizeof(float2); // 64 MiB

    if (ws_size >= ws_needed) {
        double* ws = (double*)d_ws;
        // Pass 1: l8..15, one level per XCD (8 * 2048 blocks).
        enc_sched_kernel<<<16384, 256, 0, stream>>>(inputs, table, ws, 8, 2048);
        // Pass 2: l2..7 fractional over 8 XCDs (8 * 1536 blocks).
        enc_sched_kernel<<<12288, 256, 0, stream>>>(inputs, table, ws, 2, 1536);
        // Coarse l0/l1 from LDS cube (256 blocks x 1024 thr, 85,184 B LDS).
        coarse_kernel<<<256, 1024, 22 * 22 * 22 * sizeof(double), stream>>>(
            inputs, table, ws);
        // Phase B: 2048 blocks.
        transpose_kernel<<<2048, 256, 0, stream>>>(ws, (nfloat4*)d_out);
    } else {
        enc_scatter_kernel<<<32768, 256, 0, stream>>>(inputs, table, (float2*)d_out);
    }
}